// Round 1
// baseline (241.852 us; speedup 1.0000x reference)
//
#include <hip/hip_runtime.h>

typedef __attribute__((ext_vector_type(8))) short short8;
typedef __attribute__((ext_vector_type(4))) float f32x4;
typedef unsigned int u32;
typedef unsigned short u16;

#define C_DIM 128
#define MT_MAX 7      // ceil(112/16) m-tiles (NPG=100 padded to 112)
#define XROWS 112
#define THREADS 512

__device__ __forceinline__ u16 bf16_rn(float x) {
    u32 u = __float_as_uint(x);
    u32 r = u + 0x7FFFu + ((u >> 16) & 1u);
    return (u16)(r >> 16);
}

__device__ __forceinline__ float silu_f(float x) {
    return x / (1.0f + __expf(-x));
}

__device__ __forceinline__ float dot4(float4 a, float4 b) {
    return a.x * b.x + a.y * b.y + a.z * b.z + a.w * b.w;
}

// split f32x4 -> (hi, lo) bf16 packed pairs
__device__ __forceinline__ void cvt4(float4 v, u32& hi01, u32& hi23, u32& lo01, u32& lo23) {
    u16 h0 = bf16_rn(v.x), h1 = bf16_rn(v.y), h2 = bf16_rn(v.z), h3 = bf16_rn(v.w);
    float r0 = v.x - __uint_as_float((u32)h0 << 16);
    float r1 = v.y - __uint_as_float((u32)h1 << 16);
    float r2 = v.z - __uint_as_float((u32)h2 << 16);
    float r3 = v.w - __uint_as_float((u32)h3 << 16);
    u16 l0 = bf16_rn(r0), l1 = bf16_rn(r1), l2 = bf16_rn(r2), l3 = bf16_rn(r3);
    hi01 = (u32)h0 | ((u32)h1 << 16);
    hi23 = (u32)h2 | ((u32)h3 << 16);
    lo01 = (u32)l0 | ((u32)l1 << 16);
    lo23 = (u32)l2 | ((u32)l3 << 16);
}

// rows of CG that matter: row 0 (iso), rows 4..8 (aniso m=0..4)
__constant__ float CG_TAB[6][9] = {
    {  0.5773502691896258f, 0.f, 0.f,  0.f, 0.5773502691896258f, 0.f,  0.f, 0.f, 0.5773502691896258f },
    {  0.f, 0.f, 0.7071067811865476f,  0.f, 0.f, 0.f,  0.7071067811865476f, 0.f, 0.f },
    {  0.f, 0.f, 0.f,  0.f, 0.f, 0.7071067811865476f,  0.f, 0.7071067811865476f, 0.f },
    { -0.4082482904638630f, 0.f, 0.f,  0.f, 0.8164965809277260f, 0.f,  0.f, 0.f, -0.4082482904638630f },
    {  0.f, 0.7071067811865476f, 0.f,  0.7071067811865476f, 0.f, 0.f,  0.f, 0.f, 0.f },
    { -0.7071067811865476f, 0.f, 0.f,  0.f, 0.f, 0.f,  0.f, 0.f, 0.7071067811865476f },
};

// stage a 128x128 fp32 weight matrix -> LDS bf16 hi/lo, row-major [j][k], XOR-swizzled
__device__ __forceinline__ void stage_w_mat(const float* __restrict__ Wsrc,
                                            u16* dsthi, u16* dstlo, int tid) {
    #pragma unroll 4
    for (int f = tid; f < 128 * 32; f += THREADS) {
        const int j = f >> 5, c4 = f & 31;
        float4 v = *((const float4*)Wsrc + f);
        const int ksw = (c4 * 4) ^ ((j & 7) << 3);
        u32 a, b, c, d;
        cvt4(v, a, b, c, d);
        *(uint2*)(dsthi + j * 128 + ksw) = make_uint2(a, b);
        *(uint2*)(dstlo + j * 128 + ksw) = make_uint2(c, d);
    }
}

// per-wave fused GEMM layer: acc[i][t] (i = local m-tile, t = local n-tile)
// D = Xhi*Whi + Xhi*Wlo + Xlo*Whi  (split-bf16, fp32-grade accuracy)
__device__ __forceinline__ void gemm_layer(const u16* sWhi, const u16* sWlo,
                                           const u16* sXhi, const u16* sXlo,
                                           int w, int lr, int lkg,
                                           f32x4 acc[4][2]) {
    const int mt0 = (w >> 2) * 4;           // group0: mt 0..3, group1: mt 4..6
    const int nt0 = (w & 3) * 2;
    #pragma unroll
    for (int i = 0; i < 4; ++i)
        #pragma unroll
        for (int t = 0; t < 2; ++t)
            acc[i][t] = (f32x4){0.f, 0.f, 0.f, 0.f};
    #pragma unroll
    for (int ks = 0; ks < 4; ++ks) {
        const int k0 = ks * 32 + lkg * 8;
        short8 bh[2], bl[2];
        #pragma unroll
        for (int t = 0; t < 2; ++t) {
            const int j = (nt0 + t) * 16 + lr;
            const int off = j * 128 + (k0 ^ ((j & 7) << 3));
            bh[t] = *(const short8*)(sWhi + off);
            bl[t] = *(const short8*)(sWlo + off);
        }
        #pragma unroll
        for (int i = 0; i < 4; ++i) {
            const int mt = mt0 + i;
            if (mt < MT_MAX) {
                const int row = mt * 16 + lr;
                const int off = row * 128 + (k0 ^ ((row & 7) << 3));
                short8 ah = *(const short8*)(sXhi + off);
                short8 al = *(const short8*)(sXlo + off);
                #pragma unroll
                for (int t = 0; t < 2; ++t) {
                    acc[i][t] = __builtin_amdgcn_mfma_f32_16x16x32_bf16(ah, bh[t], acc[i][t], 0, 0, 0);
                    acc[i][t] = __builtin_amdgcn_mfma_f32_16x16x32_bf16(ah, bl[t], acc[i][t], 0, 0, 0);
                    acc[i][t] = __builtin_amdgcn_mfma_f32_16x16x32_bf16(al, bh[t], acc[i][t], 0, 0, 0);
                }
            }
        }
    }
}

extern "C" __global__ void __launch_bounds__(THREADS, 1)
fused_stress(const float* __restrict__ emb,
             const float* __restrict__ W1, const float* __restrict__ b1,
             const float* __restrict__ W2, const float* __restrict__ b2,
             const float* __restrict__ W3, const float* __restrict__ b3,
             const float* __restrict__ wl2, const int* __restrict__ natoms,
             float* __restrict__ out, int NPG) {
    __shared__ u16 sWhi[128 * 128];     // 32 KB
    __shared__ u16 sWlo[128 * 128];     // 32 KB
    __shared__ u16 sXhi[XROWS * 128];   // 28 KB
    __shared__ u16 sXlo[XROWS * 128];   // 28 KB
    __shared__ float s_acc[6];          // [0]=iso sum, [1..5]=aniso sums

    const int tid = threadIdx.x;
    const int l   = tid & 63;
    const int w   = tid >> 6;           // wave 0..7
    const int lr  = l & 15;
    const int lkg = l >> 4;             // 0..3
    const int g   = blockIdx.x;
    const size_t nodebase = (size_t)g * (size_t)NPG;

    if (tid < 6) s_acc[tid] = 0.0f;
    __syncthreads();

    // ---- stage x0 rows -> sX (bf16 hi/lo, swizzled), zero-pad rows NPG..111 ----
    #pragma unroll 4
    for (int f = tid; f < XROWS * 32; f += THREADS) {
        const int row = f >> 5, c4 = f & 31;
        float4 v = make_float4(0.f, 0.f, 0.f, 0.f);
        if (row < NPG)
            v = *((const float4*)(emb + (nodebase + row) * 9 * C_DIM) + c4);
        const int ksw = (c4 * 4) ^ ((row & 7) << 3);
        u32 a, b, c, d;
        cvt4(v, a, b, c, d);
        *(uint2*)(&sXhi[row * 128 + ksw]) = make_uint2(a, b);
        *(uint2*)(&sXlo[row * 128 + ksw]) = make_uint2(c, d);
    }

    // ---- stage W1 ----
    stage_w_mat(W1, sWhi, sWlo, tid);

    // ---- aniso stream: rows 4..8 of each node, dot w_l2, accumulate per m ----
    {
        const float4 wv = *((const float4*)wl2 + (l & 31));
        float a0 = 0.f, a1 = 0.f, a2 = 0.f, a3 = 0.f, a4 = 0.f;
        for (int node = w * 2 + (l >> 5); node < NPG; node += 16) {
            const float4* p = (const float4*)(emb + (nodebase + node) * 9 * C_DIM + 4 * C_DIM) + (l & 31);
            float4 v0 = p[0];
            float4 v1 = p[32];
            float4 v2 = p[64];
            float4 v3 = p[96];
            float4 v4 = p[128];
            a0 += dot4(v0, wv);
            a1 += dot4(v1, wv);
            a2 += dot4(v2, wv);
            a3 += dot4(v3, wv);
            a4 += dot4(v4, wv);
        }
        #pragma unroll
        for (int s = 1; s < 32; s <<= 1) {
            a0 += __shfl_xor(a0, s);
            a1 += __shfl_xor(a1, s);
            a2 += __shfl_xor(a2, s);
            a3 += __shfl_xor(a3, s);
            a4 += __shfl_xor(a4, s);
        }
        if ((l & 31) == 0) {
            atomicAdd(&s_acc[1], a0);
            atomicAdd(&s_acc[2], a1);
            atomicAdd(&s_acc[3], a2);
            atomicAdd(&s_acc[4], a3);
            atomicAdd(&s_acc[5], a4);
        }
    }
    __syncthreads();

    f32x4 acc[4][2];
    const int mt0 = (w >> 2) * 4;
    const int nt0 = (w & 3) * 2;

    // ---- layer 1: h = silu(x0 @ W1^T + b1) ----
    gemm_layer(sWhi, sWlo, sXhi, sXlo, w, lr, lkg, acc);
    __syncthreads();   // everyone done reading sW (W1) and sX (x0)

    // stage W2 while writing h back into sX (disjoint LDS regions)
    stage_w_mat(W2, sWhi, sWlo, tid);
    {
        #pragma unroll
        for (int t = 0; t < 2; ++t) {
            const int j = (nt0 + t) * 16 + lr;
            const float bj = b1[j];
            #pragma unroll
            for (int i = 0; i < 4; ++i) {
                const int mt = mt0 + i;
                if (mt < MT_MAX) {
                    #pragma unroll
                    for (int r = 0; r < 4; ++r) {
                        const int row = mt * 16 + lkg * 4 + r;
                        const float hv = silu_f(acc[i][t][r] + bj);
                        const u16 hh = bf16_rn(hv);
                        const float hf = __uint_as_float((u32)hh << 16);
                        const u16 hl = bf16_rn(hv - hf);
                        const int off = row * 128 + (j ^ ((row & 7) << 3));
                        sXhi[off] = hh;
                        sXlo[off] = hl;
                    }
                }
            }
        }
    }
    __syncthreads();

    // ---- layer 2: h2 = silu(h @ W2^T + b2); s = h2 . W3 ; block-sum ----
    gemm_layer(sWhi, sWlo, sXhi, sXlo, w, lr, lkg, acc);
    {
        float w3j[2], b2j[2];
        #pragma unroll
        for (int t = 0; t < 2; ++t) {
            const int j = (nt0 + t) * 16 + lr;
            w3j[t] = W3[j];
            b2j[t] = b2[j];
        }
        #pragma unroll
        for (int i = 0; i < 4; ++i) {
            const int mt = mt0 + i;
            if (mt < MT_MAX) {
                #pragma unroll
                for (int r = 0; r < 4; ++r) {
                    float p = silu_f(acc[i][0][r] + b2j[0]) * w3j[0]
                            + silu_f(acc[i][1][r] + b2j[1]) * w3j[1];
                    p += __shfl_xor(p, 1);
                    p += __shfl_xor(p, 2);
                    p += __shfl_xor(p, 4);
                    p += __shfl_xor(p, 8);
                    const int row = mt * 16 + lkg * 4 + r;
                    if (lr == 0 && row < NPG)
                        atomicAdd(&s_acc[0], p);
                }
            }
        }
    }
    __syncthreads();

    // ---- finalize: dec = [iso, 0,0,0, aniso]; out = dec @ CG ----
    if (tid < 9) {
        const float inv = 1.0f / (float)natoms[g];
        const float iso = (s_acc[0] + (float)NPG * b3[0]) * inv;
        float o = iso * CG_TAB[0][tid];
        #pragma unroll
        for (int m = 0; m < 5; ++m)
            o += (s_acc[1 + m] * inv) * CG_TAB[1 + m][tid];
        out[(size_t)g * 9 + tid] = o;
    }
}

extern "C" void kernel_launch(void* const* d_in, const int* in_sizes, int n_in,
                              void* d_out, int out_size, void* d_ws, size_t ws_size,
                              hipStream_t stream) {
    const float* emb    = (const float*)d_in[0];
    const float* W1     = (const float*)d_in[1];
    const float* b1     = (const float*)d_in[2];
    const float* W2     = (const float*)d_in[3];
    const float* b2     = (const float*)d_in[4];
    const float* W3     = (const float*)d_in[5];
    const float* b3     = (const float*)d_in[6];
    const float* wl2    = (const float*)d_in[7];
    const int*   natoms = (const int*)d_in[9];

    const int G   = in_sizes[9];
    const int N   = in_sizes[0] / (9 * C_DIM);
    const int NPG = N / G;   // 100 for this problem; kernel supports NPG <= 112

    fused_stress<<<G, THREADS, 0, stream>>>(emb, W1, b1, W2, b2, W3, b3, wl2,
                                            natoms, (float*)d_out, NPG);
}

// Round 2
// 163.943 us; speedup vs baseline: 1.4752x; 1.4752x over previous
//
#include <hip/hip_runtime.h>

typedef __attribute__((ext_vector_type(8))) short short8;
typedef __attribute__((ext_vector_type(4))) float f32x4;
typedef unsigned int u32;
typedef unsigned short u16;

#define C_DIM 128
#define MT_MAX 7      // ceil(112/16) m-tiles (NPG=100 padded to 112)
#define XROWS 112
#define THREADS 512

// Packed MFMA B-fragments of W1/W2: [layer][half(hi,lo)][nt(8)][ks(4)][lane(64)][8] bf16.
// 128 KB total; written by prep_wpack each call, read by fused_stress.
__device__ __align__(16) u16 g_wpack[2][2][8][4][64][8];

__device__ __forceinline__ u16 bf16_rn(float x) {
    u32 u = __float_as_uint(x);
    u32 r = u + 0x7FFFu + ((u >> 16) & 1u);
    return (u16)(r >> 16);
}

__device__ __forceinline__ float silu_f(float x) {
    return x / (1.0f + __expf(-x));
}

__device__ __forceinline__ float dot4(float4 a, float4 b) {
    return a.x * b.x + a.y * b.y + a.z * b.z + a.w * b.w;
}

// split f32x4 -> (hi, lo) bf16 packed pairs
__device__ __forceinline__ void cvt4(float4 v, u32& hi01, u32& hi23, u32& lo01, u32& lo23) {
    u16 h0 = bf16_rn(v.x), h1 = bf16_rn(v.y), h2 = bf16_rn(v.z), h3 = bf16_rn(v.w);
    float r0 = v.x - __uint_as_float((u32)h0 << 16);
    float r1 = v.y - __uint_as_float((u32)h1 << 16);
    float r2 = v.z - __uint_as_float((u32)h2 << 16);
    float r3 = v.w - __uint_as_float((u32)h3 << 16);
    u16 l0 = bf16_rn(r0), l1 = bf16_rn(r1), l2 = bf16_rn(r2), l3 = bf16_rn(r3);
    hi01 = (u32)h0 | ((u32)h1 << 16);
    hi23 = (u32)h2 | ((u32)h3 << 16);
    lo01 = (u32)l0 | ((u32)l1 << 16);
    lo23 = (u32)l2 | ((u32)l3 << 16);
}

// rows of CG that matter: row 0 (iso), rows 4..8 (aniso m=0..4)
__constant__ float CG_TAB[6][9] = {
    {  0.5773502691896258f, 0.f, 0.f,  0.f, 0.5773502691896258f, 0.f,  0.f, 0.f, 0.5773502691896258f },
    {  0.f, 0.f, 0.7071067811865476f,  0.f, 0.f, 0.f,  0.7071067811865476f, 0.f, 0.f },
    {  0.f, 0.f, 0.f,  0.f, 0.f, 0.7071067811865476f,  0.f, 0.7071067811865476f, 0.f },
    { -0.4082482904638630f, 0.f, 0.f,  0.f, 0.8164965809277260f, 0.f,  0.f, 0.f, -0.4082482904638630f },
    {  0.f, 0.7071067811865476f, 0.f,  0.7071067811865476f, 0.f, 0.f,  0.f, 0.f, 0.f },
    { -0.7071067811865476f, 0.f, 0.f,  0.f, 0.f, 0.f,  0.f, 0.f, 0.7071067811865476f },
};

// one-shot: pack W1/W2 into MFMA B-fragment order, bf16 hi/lo planes
extern "C" __global__ void __launch_bounds__(512)
prep_wpack(const float* __restrict__ W1, const float* __restrict__ W2) {
    const int t = blockIdx.x * 512 + threadIdx.x;    // 0..4095
    const int layer = t >> 11;
    const int rem   = t & 2047;
    const int nt    = rem >> 8;
    const int ks    = (rem >> 6) & 3;
    const int lane  = rem & 63;
    const int j  = nt * 16 + (lane & 15);
    const int k0 = ks * 32 + (lane >> 4) * 8;
    const float* W = layer ? W2 : W1;
    const float* src = W + j * C_DIM + k0;
    short8 vh, vl;
    #pragma unroll
    for (int i = 0; i < 8; ++i) {
        const float v = src[i];
        const u16 h = bf16_rn(v);
        vh[i] = (short)h;
        vl[i] = (short)bf16_rn(v - __uint_as_float((u32)h << 16));
    }
    *(short8*)&g_wpack[layer][0][nt][ks][lane][0] = vh;
    *(short8*)&g_wpack[layer][1][nt][ks][lane][0] = vl;
}

// per-wave fused GEMM layer, B-fragments streamed from packed global (L2)
// D = Xhi*Whi + Xhi*Wlo + Xlo*Whi  (split-bf16, fp32-grade accuracy)
__device__ __forceinline__ void gemm_layer_pk(const u16* __restrict__ wpk_hi,
                                              const u16* __restrict__ wpk_lo,
                                              const u16* sXhi, const u16* sXlo,
                                              int w, int l, f32x4 acc[4][2]) {
    const int mt0 = (w >> 2) * 4;
    const int nt0 = (w & 3) * 2;
    const int lr  = l & 15;
    #pragma unroll
    for (int i = 0; i < 4; ++i)
        #pragma unroll
        for (int t = 0; t < 2; ++t)
            acc[i][t] = (f32x4){0.f, 0.f, 0.f, 0.f};
    #pragma unroll
    for (int ks = 0; ks < 4; ++ks) {
        const int k0 = ks * 32 + (l >> 4) * 8;
        short8 bh[2], bl[2];
        #pragma unroll
        for (int t = 0; t < 2; ++t) {
            const int idx = (((nt0 + t) * 4 + ks) * 64 + l) * 8;
            bh[t] = *(const short8*)(wpk_hi + idx);
            bl[t] = *(const short8*)(wpk_lo + idx);
        }
        #pragma unroll
        for (int i = 0; i < 4; ++i) {
            const int mt = mt0 + i;
            if (mt < MT_MAX) {
                const int row = mt * 16 + lr;
                const int off = row * 128 + (k0 ^ ((row & 7) << 3));
                short8 ah = *(const short8*)(sXhi + off);
                short8 al = *(const short8*)(sXlo + off);
                #pragma unroll
                for (int t = 0; t < 2; ++t) {
                    acc[i][t] = __builtin_amdgcn_mfma_f32_16x16x32_bf16(ah, bh[t], acc[i][t], 0, 0, 0);
                    acc[i][t] = __builtin_amdgcn_mfma_f32_16x16x32_bf16(ah, bl[t], acc[i][t], 0, 0, 0);
                    acc[i][t] = __builtin_amdgcn_mfma_f32_16x16x32_bf16(al, bh[t], acc[i][t], 0, 0, 0);
                }
            }
        }
    }
}

extern "C" __global__ void __launch_bounds__(THREADS, 4)
fused_stress(const float* __restrict__ emb,
             const float* __restrict__ b1,
             const float* __restrict__ b2,
             const float* __restrict__ W3, const float* __restrict__ b3,
             const float* __restrict__ wl2, const int* __restrict__ natoms,
             float* __restrict__ out, int NPG) {
    __shared__ u16 sXhi[XROWS * 128];   // 28 KB
    __shared__ u16 sXlo[XROWS * 128];   // 28 KB
    __shared__ float s_acc[6];          // [0]=iso sum, [1..5]=aniso sums

    const int tid = threadIdx.x;
    const int l   = tid & 63;
    const int w   = tid >> 6;           // wave 0..7
    const int lr  = l & 15;
    const int lkg = l >> 4;             // 0..3
    const int g   = blockIdx.x;
    const size_t nodebase = (size_t)g * (size_t)NPG;

    if (tid < 6) s_acc[tid] = 0.0f;

    // ---- stage x0 rows -> sX (bf16 hi/lo, swizzled), zero-pad rows NPG..111 ----
    #pragma unroll 4
    for (int f = tid; f < XROWS * 32; f += THREADS) {
        const int row = f >> 5, c4 = f & 31;
        float4 v = make_float4(0.f, 0.f, 0.f, 0.f);
        if (row < NPG)
            v = *((const float4*)(emb + (nodebase + row) * 9 * C_DIM) + c4);
        const int ksw = (c4 * 4) ^ ((row & 7) << 3);
        u32 a, b, c, d;
        cvt4(v, a, b, c, d);
        *(uint2*)(&sXhi[row * 128 + ksw]) = make_uint2(a, b);
        *(uint2*)(&sXlo[row * 128 + ksw]) = make_uint2(c, d);
    }

    // ---- aniso stream: rows 4..8 of each node, dot w_l2, accumulate per m ----
    {
        const float4 wv = *((const float4*)wl2 + (l & 31));
        float a0 = 0.f, a1 = 0.f, a2 = 0.f, a3 = 0.f, a4 = 0.f;
        for (int node = w * 2 + (l >> 5); node < NPG; node += 16) {
            const float4* p = (const float4*)(emb + (nodebase + node) * 9 * C_DIM + 4 * C_DIM) + (l & 31);
            float4 v0 = p[0];
            float4 v1 = p[32];
            float4 v2 = p[64];
            float4 v3 = p[96];
            float4 v4 = p[128];
            a0 += dot4(v0, wv);
            a1 += dot4(v1, wv);
            a2 += dot4(v2, wv);
            a3 += dot4(v3, wv);
            a4 += dot4(v4, wv);
        }
        #pragma unroll
        for (int s = 1; s < 32; s <<= 1) {
            a0 += __shfl_xor(a0, s);
            a1 += __shfl_xor(a1, s);
            a2 += __shfl_xor(a2, s);
            a3 += __shfl_xor(a3, s);
            a4 += __shfl_xor(a4, s);
        }
        if ((l & 31) == 0) {
            atomicAdd(&s_acc[1], a0);
            atomicAdd(&s_acc[2], a1);
            atomicAdd(&s_acc[3], a2);
            atomicAdd(&s_acc[4], a3);
            atomicAdd(&s_acc[5], a4);
        }
    }
    __syncthreads();

    f32x4 acc[4][2];
    const int mt0 = (w >> 2) * 4;
    const int nt0 = (w & 3) * 2;

    // ---- layer 1: h = silu(x0 @ W1^T + b1) ----
    gemm_layer_pk(&g_wpack[0][0][0][0][0][0], &g_wpack[0][1][0][0][0][0],
                  sXhi, sXlo, w, l, acc);
    __syncthreads();   // everyone done reading sX (x0)

    // write h back into sX (bf16 hi/lo, swizzled)
    {
        #pragma unroll
        for (int t = 0; t < 2; ++t) {
            const int j = (nt0 + t) * 16 + lr;
            const float bj = b1[j];
            #pragma unroll
            for (int i = 0; i < 4; ++i) {
                const int mt = mt0 + i;
                if (mt < MT_MAX) {
                    #pragma unroll
                    for (int r = 0; r < 4; ++r) {
                        const int row = mt * 16 + lkg * 4 + r;
                        const float hv = silu_f(acc[i][t][r] + bj);
                        const u16 hh = bf16_rn(hv);
                        const float hf = __uint_as_float((u32)hh << 16);
                        const u16 hl = bf16_rn(hv - hf);
                        const int off = row * 128 + (j ^ ((row & 7) << 3));
                        sXhi[off] = hh;
                        sXlo[off] = hl;
                    }
                }
            }
        }
    }
    __syncthreads();

    // ---- layer 2: h2 = silu(h @ W2^T + b2); s = h2 . W3 ; block-sum ----
    gemm_layer_pk(&g_wpack[1][0][0][0][0][0], &g_wpack[1][1][0][0][0][0],
                  sXhi, sXlo, w, l, acc);
    {
        float w3j[2], b2j[2];
        #pragma unroll
        for (int t = 0; t < 2; ++t) {
            const int j = (nt0 + t) * 16 + lr;
            w3j[t] = W3[j];
            b2j[t] = b2[j];
        }
        #pragma unroll
        for (int i = 0; i < 4; ++i) {
            const int mt = mt0 + i;
            if (mt < MT_MAX) {
                #pragma unroll
                for (int r = 0; r < 4; ++r) {
                    float p = silu_f(acc[i][0][r] + b2j[0]) * w3j[0]
                            + silu_f(acc[i][1][r] + b2j[1]) * w3j[1];
                    p += __shfl_xor(p, 1);
                    p += __shfl_xor(p, 2);
                    p += __shfl_xor(p, 4);
                    p += __shfl_xor(p, 8);
                    const int row = mt * 16 + lkg * 4 + r;
                    if (lr == 0 && row < NPG)
                        atomicAdd(&s_acc[0], p);
                }
            }
        }
    }
    __syncthreads();

    // ---- finalize: dec = [iso, 0,0,0, aniso]; out = dec @ CG ----
    if (tid < 9) {
        const float inv = 1.0f / (float)natoms[g];
        const float iso = (s_acc[0] + (float)NPG * b3[0]) * inv;
        float o = iso * CG_TAB[0][tid];
        #pragma unroll
        for (int m = 0; m < 5; ++m)
            o += (s_acc[1 + m] * inv) * CG_TAB[1 + m][tid];
        out[(size_t)g * 9 + tid] = o;
    }
}

extern "C" void kernel_launch(void* const* d_in, const int* in_sizes, int n_in,
                              void* d_out, int out_size, void* d_ws, size_t ws_size,
                              hipStream_t stream) {
    const float* emb    = (const float*)d_in[0];
    const float* W1     = (const float*)d_in[1];
    const float* b1     = (const float*)d_in[2];
    const float* W2     = (const float*)d_in[3];
    const float* b2     = (const float*)d_in[4];
    const float* W3     = (const float*)d_in[5];
    const float* b3     = (const float*)d_in[6];
    const float* wl2    = (const float*)d_in[7];
    const int*   natoms = (const int*)d_in[9];

    const int G   = in_sizes[9];
    const int N   = in_sizes[0] / (9 * C_DIM);
    const int NPG = N / G;   // 100 for this problem; kernel supports NPG <= 112

    prep_wpack<<<8, 512, 0, stream>>>(W1, W2);
    fused_stress<<<G, THREADS, 0, stream>>>(emb, b1, b2, W3, b3, wl2,
                                            natoms, (float*)d_out, NPG);
}